// Round 4
// baseline (1289.598 us; speedup 1.0000x reference)
//
#include <hip/hip_runtime.h>

// Relation_5841155522972 — talking-heads attention, straight-through hard select.
// out[b,i,h*64+d] = v[b, argmax_j n[b,h,i,j], h*64+d],
// n = LayerNorm_h( softmax_j(QK^T/32) mixed by Wt ).
//
// R9: occupancy via SMALLER LDS TILE (lesson from R6-R8: at the ~128-VGPR
// working set the HW won't co-schedule two 8-wave blocks; 70KB ptile capped
// the kernel at 8 waves/CU forever). attn_select_v8: tile 16i x 32j x 16h,
// ptile 32*271*4B ~= 34.7KB (+2KB red) -> 4 blocks/CU x 4 waves = 16 waves/CU
// (4/SIMD, the VGPR=128 ceiling). Dot keeps v5's 2-VMEM/16-FMA economy by
// covering 2 heads per wave-round: lane = hp(2h) x jg(8x4j) x ig(4x4i),
// float4 q x float4 k, 2 rounds x 2h x 4 waves = 16h. Mix = v5 verbatim with
// jj loop 8 (32 j), merge xor 4,8. __launch_bounds__(256,4) pins VGPR<=128
// (= v5's measured natural allocation; no spill expected).
//  K1  qkv_gemm       : unchanged fp32 GEMM (qT/kT transposed, V straight).
//  K2a attn_stats_v5  : unchanged (no-LDS, zero-barrier).
//  K2b attn_select_v8 : 36KB-tile select, grid 8192 x 256 thr.
//  K2c gather_v4      : unchanged.
// ws: 52.5 MB.

#define FMA4(cc, av, bv) \
  cc.x = fmaf(av, bv.x, cc.x); cc.y = fmaf(av, bv.y, cc.y); \
  cc.z = fmaf(av, bv.z, cc.z); cc.w = fmaf(av, bv.w, cc.w);

__global__ __launch_bounds__(256) void qkv_gemm(
    const float* __restrict__ X, const float* __restrict__ Wq,
    const float* __restrict__ Wkv, float* __restrict__ qT,
    float* __restrict__ kT, float* __restrict__ V)
{
  __shared__ __align__(16) float As[16 * 132];
  __shared__ __align__(16) float Bs[16 * 132];
  __shared__ __align__(16) float tb[128 * 32];

  const int t  = threadIdx.x;
  const int bn = blockIdx.x;
  const int bm = blockIdx.y;
  const int m0 = bm * 128, n0 = bn * 128;
  const int ty = t >> 4, tx = t & 15;

  const float* Wbase = (n0 < 1024) ? Wq : Wkv;
  const int nw0 = (n0 < 1024) ? n0 : (n0 - 1024);

  float4 c2[8][2];
#pragma unroll
  for (int a = 0; a < 8; a++) {
    c2[a][0] = make_float4(0.f, 0.f, 0.f, 0.f);
    c2[a][1] = make_float4(0.f, 0.f, 0.f, 0.f);
  }

  const int lr = t >> 1;
  const int lh = t & 1;

  const float4* As4 = (const float4*)As;
  const float4* Bs4 = (const float4*)Bs;

  for (int kb = 0; kb < 64; kb++) {
    const int k0 = kb * 16;
    __syncthreads();
#pragma unroll
    for (int s = 0; s < 2; s++) {
      const int kk = lh * 8 + s * 4;
      float4 av = *(const float4*)&X[(size_t)(m0 + lr) * 1024 + k0 + kk];
      float4 bv = *(const float4*)&Wbase[(size_t)(nw0 + lr) * 1024 + k0 + kk];
      As[(kk + 0) * 132 + lr] = av.x;
      As[(kk + 1) * 132 + lr] = av.y;
      As[(kk + 2) * 132 + lr] = av.z;
      As[(kk + 3) * 132 + lr] = av.w;
      Bs[(kk + 0) * 132 + lr] = bv.x;
      Bs[(kk + 1) * 132 + lr] = bv.y;
      Bs[(kk + 2) * 132 + lr] = bv.z;
      Bs[(kk + 3) * 132 + lr] = bv.w;
    }
    __syncthreads();
#pragma unroll
    for (int kk = 0; kk < 16; kk++) {
      float4 a0 = As4[kk * 33 + ty * 2];
      float4 a1 = As4[kk * 33 + ty * 2 + 1];
      float4 b0 = Bs4[kk * 33 + tx];
      float4 b1 = Bs4[kk * 33 + 16 + tx];
      FMA4(c2[0][0], a0.x, b0); FMA4(c2[0][1], a0.x, b1);
      FMA4(c2[1][0], a0.y, b0); FMA4(c2[1][1], a0.y, b1);
      FMA4(c2[2][0], a0.z, b0); FMA4(c2[2][1], a0.z, b1);
      FMA4(c2[3][0], a0.w, b0); FMA4(c2[3][1], a0.w, b1);
      FMA4(c2[4][0], a1.x, b0); FMA4(c2[4][1], a1.x, b1);
      FMA4(c2[5][0], a1.y, b0); FMA4(c2[5][1], a1.y, b1);
      FMA4(c2[6][0], a1.z, b0); FMA4(c2[6][1], a1.z, b1);
      FMA4(c2[7][0], a1.w, b0); FMA4(c2[7][1], a1.w, b1);
    }
  }

  if (n0 >= 2048) {
    const int nv0 = n0 - 2048;
#pragma unroll
    for (int a = 0; a < 8; a++) {
      *(float4*)&V[(size_t)(m0 + ty * 8 + a) * 1024 + nv0 + tx * 4]      = c2[a][0];
      *(float4*)&V[(size_t)(m0 + ty * 8 + a) * 1024 + nv0 + 64 + tx * 4] = c2[a][1];
    }
    return;
  }

  float* T = (n0 < 1024) ? qT : kT;
  const int nt0 = (n0 < 1024) ? n0 : (n0 - 1024);
  const int bB = m0 >> 10;
  const int i0 = m0 & 1023;
#pragma unroll
  for (int r = 0; r < 4; r++) {
    __syncthreads();
    if ((tx >> 3) == (r & 1)) {
      const int c0 = (tx & 7) * 4;
#pragma unroll
      for (int a = 0; a < 8; a++) {
        const int m = ty * 8 + a;
        float4 val = c2[a][r >> 1];
        tb[m * 32 + ((c0 + 0 + m) & 31)] = val.x;
        tb[m * 32 + ((c0 + 1 + m) & 31)] = val.y;
        tb[m * 32 + ((c0 + 2 + m) & 31)] = val.z;
        tb[m * 32 + ((c0 + 3 + m) & 31)] = val.w;
      }
    }
    __syncthreads();
    const int nl = t >> 3, mq = t & 7;
    float* Trow = T + (size_t)(bB * 1024 + nt0 + (r >> 1) * 64 + (r & 1) * 32 + nl) * 1024 + i0;
#pragma unroll
    for (int l = 0; l < 4; l++) {
      const int mb = (l * 8 + mq) * 4;
      float4 o;
      o.x = tb[(mb + 0) * 32 + ((nl + mb + 0) & 31)];
      o.y = tb[(mb + 1) * 32 + ((nl + mb + 1) & 31)];
      o.z = tb[(mb + 2) * 32 + ((nl + mb + 2) & 31)];
      o.w = tb[(mb + 3) * 32 + ((nl + mb + 3) & 31)];
      *(float4*)(Trow + mb) = o;
    }
  }
}

// ---------------------------------------------------------------------------
// K2a v5: no-LDS stats, float4 x float4 register tile. (unchanged)
// grid = b(4) x it(32 x 32i) x js(8 x 128j) = 1024. wave = 8i x 128j:
// lane: ih = l>>5 (i-quad), jg = l&31 (j-quad). acc[4][4]. Zero barriers.
// ---------------------------------------------------------------------------
__global__ __launch_bounds__(256) void attn_stats_v5(
    const float* __restrict__ qT, const float* __restrict__ kT,
    float* __restrict__ Mm, float* __restrict__ Ml)
{
  const int t  = threadIdx.x;
  const int bx = blockIdx.x;
  const int b  = bx >> 8;
  const int it = (bx >> 3) & 31;
  const int js = bx & 7;
  const int wv = t >> 6;
  const int l  = t & 63;
  const int ih = l >> 5;
  const int jg = l & 31;
  const int i0w = __builtin_amdgcn_readfirstlane(it * 32 + wv * 8);
  const int iq = i0w + ih * 4;
  const int jq = js * 128 + jg * 4;

  const float scale = 0.03125f;

  for (int h = 0; h < 16; h++) {
    const size_t base = (size_t)(b * 1024 + h * 64) * 1024;
    float4 acc[4];
#pragma unroll
    for (int ii = 0; ii < 4; ii++) acc[ii] = make_float4(0.f, 0.f, 0.f, 0.f);

#pragma unroll 4
    for (int d = 0; d < 64; d++) {
      const float4 qv = *(const float4*)(qT + base + (size_t)d * 1024 + iq);
      const float4 kv = *(const float4*)(kT + base + (size_t)d * 1024 + jq);
      FMA4(acc[0], qv.x, kv);
      FMA4(acc[1], qv.y, kv);
      FMA4(acc[2], qv.z, kv);
      FMA4(acc[3], qv.w, kv);
    }

#pragma unroll
    for (int ii = 0; ii < 4; ii++) {
      const float s0 = acc[ii].x * scale;
      const float s1 = acc[ii].y * scale;
      const float s2 = acc[ii].z * scale;
      const float s3 = acc[ii].w * scale;
      float mx = fmaxf(fmaxf(s0, s1), fmaxf(s2, s3));
      mx = fmaxf(mx, __shfl_xor(mx, 1));
      mx = fmaxf(mx, __shfl_xor(mx, 2));
      mx = fmaxf(mx, __shfl_xor(mx, 4));
      mx = fmaxf(mx, __shfl_xor(mx, 8));
      mx = fmaxf(mx, __shfl_xor(mx, 16));
      float ss = __expf(s0 - mx) + __expf(s1 - mx) +
                 __expf(s2 - mx) + __expf(s3 - mx);
      ss += __shfl_xor(ss, 1);
      ss += __shfl_xor(ss, 2);
      ss += __shfl_xor(ss, 4);
      ss += __shfl_xor(ss, 8);
      ss += __shfl_xor(ss, 16);
      if (jg == ii) {
        const int idx = (((b * 16 + h) * 1024 + iq + ii) << 3) + js;
        Mm[idx] = mx;
        Ml[idx] = ss;
      }
    }
  }
}

// packed key: monotone(float) << 32 | (1023 - j); atomicMax == (>, tie: min j)
__device__ inline unsigned long long mkkey(float v, int j) {
  unsigned u = __float_as_uint(v);
  u = (u & 0x80000000u) ? ~u : (u | 0x80000000u);
  return ((unsigned long long)u << 32) | (unsigned)(1023 - j);
}

// ---------------------------------------------------------------------------
// K2b v8: grid = b(4) x it(64 x 16i) x js(32 x 32j) = 8192 blocks, 256 thr.
// Tile 16i x 32j x 16h. LDS: ptile 32*271 f + 512 red = 36.7KB ->
// 4 blocks/CU x 4 waves = 16 waves/CU (4/SIMD).
// Dot: 2 rounds; per round a wave covers 16i x 32j x 2h.
//   lane: hp = l&1 (head pair), jg = (l>>1)&7 (8 x 4j), ig = l>>4 (4 x 4i);
//   per-lane 4i x 4j for h = wv*4 + hr*2 + hp; float4 q x float4 k
//   (2 VMEM / 16 FMA — v5's verified economy).
// p -> ptile[j*271 + iL*17 + hrot], hrot = (h + j>>2)&15 (v5 rotation).
// Mix: v5 verbatim (i2=t>>4, g=(t>>2)&3, hq=t&3), jj loop over 8 (32 j),
// merge xor 4,8; packed atomicMax.
// ---------------------------------------------------------------------------
__global__ __launch_bounds__(256, 4) void attn_select_v8(
    const float* __restrict__ qT, const float* __restrict__ kT,
    const float* __restrict__ Mm, const float* __restrict__ Ml,
    const float* __restrict__ Wt, const float* __restrict__ ln_g,
    const float* __restrict__ ln_b, unsigned long long* __restrict__ HiKey)
{
  __shared__ __align__(16) float smem[32 * 271 + 512];
  float* ptile = smem;                 // j*271 + i_local*17 + hrot
  float* mred  = smem + 32 * 271;      // [h*16 + i_local]
  float* rred  = mred + 256;

  const int t  = threadIdx.x;
  const int bx = blockIdx.x;
  const int b  = bx >> 11;
  const int it = (bx >> 5) & 63;
  const int js = bx & 31;
  const int i0 = it << 4;
  const int j0 = js << 5;

  const float scale = 0.03125f;

  // prologue: merge-8 slice stats (t == h*16 + i_local)
  {
    const int base = (((b * 16 + (t >> 4)) * 1024 + i0 + (t & 15)) << 3);
    const float4 ma = *(const float4*)&Mm[base];
    const float4 mb = *(const float4*)&Mm[base + 4];
    const float4 la = *(const float4*)&Ml[base];
    const float4 lb = *(const float4*)&Ml[base + 4];
    float M = fmaxf(fmaxf(fmaxf(ma.x, ma.y), fmaxf(ma.z, ma.w)),
                    fmaxf(fmaxf(mb.x, mb.y), fmaxf(mb.z, mb.w)));
    float L = la.x * __expf(ma.x - M) + la.y * __expf(ma.y - M) +
              la.z * __expf(ma.z - M) + la.w * __expf(ma.w - M) +
              lb.x * __expf(mb.x - M) + lb.y * __expf(mb.y - M) +
              lb.z * __expf(mb.z - M) + lb.w * __expf(mb.w - M);
    mred[t] = M;
    rred[t] = 1.0f / L;
  }
  __syncthreads();

  // ---- dot phase: 2 rounds x (16i x 32j x 2h) per wave ----
  const int wv = t >> 6;
  const int l  = t & 63;
  const int hp = l & 1;
  const int jg = (l >> 1) & 7;
  const int ig = l >> 4;
  const int iq = i0 + ig * 4;
  const int jcol = j0 + jg * 4;

#pragma unroll
  for (int hr = 0; hr < 2; hr++) {
    const int h = wv * 4 + hr * 2 + hp;
    const size_t base = (size_t)(b * 1024 + h * 64) * 1024;
    float4 acc[4];
#pragma unroll
    for (int ii = 0; ii < 4; ii++) acc[ii] = make_float4(0.f, 0.f, 0.f, 0.f);

#pragma unroll 4
    for (int d = 0; d < 64; d++) {
      const float4 qv = *(const float4*)(qT + base + (size_t)d * 1024 + iq);
      const float4 kv = *(const float4*)(kT + base + (size_t)d * 1024 + jcol);
      FMA4(acc[0], qv.x, kv);
      FMA4(acc[1], qv.y, kv);
      FMA4(acc[2], qv.z, kv);
      FMA4(acc[3], qv.w, kv);
    }

    const int hrot = (h + jg) & 15;   // j>>2 == jg for this lane's 4 j
#pragma unroll
    for (int ii = 0; ii < 4; ii++) {
      const int iL = ig * 4 + ii;
      const float m = mred[h * 16 + iL];
      const float r = rred[h * 16 + iL];
      const float a4[4] = {acc[ii].x, acc[ii].y, acc[ii].z, acc[ii].w};
#pragma unroll
      for (int jj = 0; jj < 4; jj++) {
        const int j = jg * 4 + jj;
        const float p = __expf(a4[jj] * scale - m) * r;
        ptile[j * 271 + iL * 17 + hrot] = p;
      }
    }
  }
  __syncthreads();

  // ---- mix phase: i2 = t>>4 (16 i), g = (t>>2)&3 (4 x 8j), hq = t&3 ----
  const int i2 = t >> 4;
  const int g  = (t >> 2) & 3;
  const int hq = t & 3;

  float wtr[4][16], gr[4], br[4];
#pragma unroll
  for (int a = 0; a < 4; a++) {
#pragma unroll
    for (int h2 = 0; h2 < 16; h2++) wtr[a][h2] = Wt[(hq * 4 + a) * 16 + h2];
    gr[a] = ln_g[hq * 4 + a];
    br[a] = ln_b[hq * 4 + a];
  }
  float bv[4]; int bix[4];
#pragma unroll
  for (int a = 0; a < 4; a++) { bv[a] = -1e30f; bix[a] = 0; }

#pragma unroll
  for (int jj = 0; jj < 8; jj++) {
    const int j = g * 8 + jj;
    const int jr = j >> 2;
    float pv[16];
#pragma unroll
    for (int h2 = 0; h2 < 16; h2++)
      pv[h2] = ptile[j * 271 + i2 * 17 + ((h2 + jr) & 15)];
    float mix[4];
#pragma unroll
    for (int a = 0; a < 4; a++) {
      float s0 = 0.f;
#pragma unroll
      for (int h2 = 0; h2 < 16; h2++) s0 = fmaf(pv[h2], wtr[a][h2], s0);
      mix[a] = s0;
    }
    float s1 = mix[0] + mix[1] + mix[2] + mix[3];
    s1 += __shfl_xor(s1, 1);
    s1 += __shfl_xor(s1, 2);
    const float mu = s1 * 0.0625f;
    float s2 = 0.f;
#pragma unroll
    for (int a = 0; a < 4; a++) { const float dd = mix[a] - mu; s2 = fmaf(dd, dd, s2); }
    s2 += __shfl_xor(s2, 1);
    s2 += __shfl_xor(s2, 2);
    const float rstd = rsqrtf(s2 * 0.0625f + 1e-5f);
    const int jg2 = j0 + j;
#pragma unroll
    for (int a = 0; a < 4; a++) {
      const float nv = (mix[a] - mu) * rstd * gr[a] + br[a];
      if (nv > bv[a]) { bv[a] = nv; bix[a] = jg2; }
    }
  }

  // merge over the 4 g-lanes (ties -> smaller j), then one atomic per (a,i)
#pragma unroll
  for (int a = 0; a < 4; a++) {
    float v = bv[a]; int ix = bix[a];
    {
      const float ov = __shfl_xor(v, 4);
      const int oi = __shfl_xor(ix, 4);
      if (ov > v || (ov == v && oi < ix)) { v = ov; ix = oi; }
    }
    {
      const float ov = __shfl_xor(v, 8);
      const int oi = __shfl_xor(ix, 8);
      if (ov > v || (ov == v && oi < ix)) { v = ov; ix = oi; }
    }
    bv[a] = v; bix[a] = ix;
  }

  if (g == 0) {
#pragma unroll
    for (int a = 0; a < 4; a++) {
      const int cell = (b * 16 + hq * 4 + a) * 1024 + i0 + i2;
      atomicMax(&HiKey[cell], mkkey(bv[a], bix[a]));
    }
  }
}

// ---------------------------------------------------------------------------
// K2c: decode key -> gather V rows (unchanged).
// ---------------------------------------------------------------------------
__global__ __launch_bounds__(256) void gather_v4(
    const unsigned long long* __restrict__ HiKey, const float* __restrict__ V,
    float* __restrict__ out)
{
  const int t  = threadIdx.x;
  const int bx = blockIdx.x;
  const int b  = bx >> 6;
  const int it = bx & 63;
  const int i2 = t >> 4;
  const int h  = t & 15;

  const unsigned long long key = HiKey[(b * 16 + h) * 1024 + it * 16 + i2];
  const int j = 1023 - (int)(unsigned)(key & 0xFFFFFFFFull);

  const float* vs = V + (size_t)(b * 1024 + j) * 1024 + h * 64;
  float* dst = out + (size_t)(b * 1024 + it * 16 + i2) * 1024 + h * 64;
#pragma unroll
  for (int w = 0; w < 16; w++)
    *(float4*)(dst + w * 4) = *(const float4*)(vs + w * 4);
}

extern "C" void kernel_launch(void* const* d_in, const int* in_sizes, int n_in,
                              void* d_out, int out_size, void* d_ws, size_t ws_size,
                              hipStream_t stream) {
  const float* x   = (const float*)d_in[0];
  const float* Wq  = (const float*)d_in[1];
  const float* Wkv = (const float*)d_in[2];
  const float* Wt  = (const float*)d_in[3];
  const float* lng = (const float*)d_in[4];
  const float* lnb = (const float*)d_in[5];
  float* out = (float*)d_out;
  float* ws  = (float*)d_ws;                          // 52.5 MB used
  float* qT = ws;                                     // 4M f
  float* kT = ws + (size_t)4 * 1024 * 1024;           // 4M f
  float* V  = ws + (size_t)8 * 1024 * 1024;           // 4M f
  float* Mm = ws + (size_t)12 * 1024 * 1024;          // 512K f
  float* Ml = Mm + 524288;                            // 512K f
  unsigned long long* HiKey =
      (unsigned long long*)(ws + (size_t)13 * 1024 * 1024);  // 64K x 8B

  hipLaunchKernelGGL(qkv_gemm, dim3(24, 32), dim3(256), 0, stream,
                     x, Wq, Wkv, qT, kT, V);
  hipMemsetAsync(HiKey, 0, (size_t)65536 * 8, stream);
  hipLaunchKernelGGL(attn_stats_v5, dim3(1024), dim3(256), 0, stream,
                     qT, kT, Mm, Ml);
  hipLaunchKernelGGL(attn_select_v8, dim3(8192), dim3(256), 0, stream,
                     qT, kT, Mm, Ml, Wt, lng, lnb, HiKey);
  hipLaunchKernelGGL(gather_v4, dim3(256), dim3(256), 0, stream,
                     HiKey, V, out);
}

// Round 5
// 1164.059 us; speedup vs baseline: 1.1078x; 1.1078x over previous
//
#include <hip/hip_runtime.h>

// Relation_5841155522972 — talking-heads attention, straight-through hard select.
// out[b,i,h*64+d] = v[b, argmax_j n[b,h,i,j], h*64+d],
// n = LayerNorm_h( softmax_j(QK^T/32) mixed by Wt ).
//
// R10: v8 minus the register cap. Empirical toolchain rule (R6/R8/R9):
// __launch_bounds__ arg2=4 forces a 64-VGPR budget regardless of block size
// -> wtr[4][16] spills (v8: WRITE 785MB, VALUBusy 22%). arg2 absent -> natural
// 128 VGPR (v5 measured, identical working set). With the 36.8KB ptile both
// limits agree at 16 waves/CU: LDS 4 blocks x 4 waves == VGPR-128 4 waves/SIMD.
//  K1  qkv_gemm       : unchanged fp32 GEMM (qT/kT transposed, V straight).
//  K2a attn_stats_v5  : unchanged (no-LDS, zero-barrier).
//  K2b attn_select_v9 : v8 tile (16i x 32j x 16h), plain __launch_bounds__(256).
//  K2c gather_v4      : unchanged.
// ws: 52.5 MB.

#define FMA4(cc, av, bv) \
  cc.x = fmaf(av, bv.x, cc.x); cc.y = fmaf(av, bv.y, cc.y); \
  cc.z = fmaf(av, bv.z, cc.z); cc.w = fmaf(av, bv.w, cc.w);

__global__ __launch_bounds__(256) void qkv_gemm(
    const float* __restrict__ X, const float* __restrict__ Wq,
    const float* __restrict__ Wkv, float* __restrict__ qT,
    float* __restrict__ kT, float* __restrict__ V)
{
  __shared__ __align__(16) float As[16 * 132];
  __shared__ __align__(16) float Bs[16 * 132];
  __shared__ __align__(16) float tb[128 * 32];

  const int t  = threadIdx.x;
  const int bn = blockIdx.x;
  const int bm = blockIdx.y;
  const int m0 = bm * 128, n0 = bn * 128;
  const int ty = t >> 4, tx = t & 15;

  const float* Wbase = (n0 < 1024) ? Wq : Wkv;
  const int nw0 = (n0 < 1024) ? n0 : (n0 - 1024);

  float4 c2[8][2];
#pragma unroll
  for (int a = 0; a < 8; a++) {
    c2[a][0] = make_float4(0.f, 0.f, 0.f, 0.f);
    c2[a][1] = make_float4(0.f, 0.f, 0.f, 0.f);
  }

  const int lr = t >> 1;
  const int lh = t & 1;

  const float4* As4 = (const float4*)As;
  const float4* Bs4 = (const float4*)Bs;

  for (int kb = 0; kb < 64; kb++) {
    const int k0 = kb * 16;
    __syncthreads();
#pragma unroll
    for (int s = 0; s < 2; s++) {
      const int kk = lh * 8 + s * 4;
      float4 av = *(const float4*)&X[(size_t)(m0 + lr) * 1024 + k0 + kk];
      float4 bv = *(const float4*)&Wbase[(size_t)(nw0 + lr) * 1024 + k0 + kk];
      As[(kk + 0) * 132 + lr] = av.x;
      As[(kk + 1) * 132 + lr] = av.y;
      As[(kk + 2) * 132 + lr] = av.z;
      As[(kk + 3) * 132 + lr] = av.w;
      Bs[(kk + 0) * 132 + lr] = bv.x;
      Bs[(kk + 1) * 132 + lr] = bv.y;
      Bs[(kk + 2) * 132 + lr] = bv.z;
      Bs[(kk + 3) * 132 + lr] = bv.w;
    }
    __syncthreads();
#pragma unroll
    for (int kk = 0; kk < 16; kk++) {
      float4 a0 = As4[kk * 33 + ty * 2];
      float4 a1 = As4[kk * 33 + ty * 2 + 1];
      float4 b0 = Bs4[kk * 33 + tx];
      float4 b1 = Bs4[kk * 33 + 16 + tx];
      FMA4(c2[0][0], a0.x, b0); FMA4(c2[0][1], a0.x, b1);
      FMA4(c2[1][0], a0.y, b0); FMA4(c2[1][1], a0.y, b1);
      FMA4(c2[2][0], a0.z, b0); FMA4(c2[2][1], a0.z, b1);
      FMA4(c2[3][0], a0.w, b0); FMA4(c2[3][1], a0.w, b1);
      FMA4(c2[4][0], a1.x, b0); FMA4(c2[4][1], a1.x, b1);
      FMA4(c2[5][0], a1.y, b0); FMA4(c2[5][1], a1.y, b1);
      FMA4(c2[6][0], a1.z, b0); FMA4(c2[6][1], a1.z, b1);
      FMA4(c2[7][0], a1.w, b0); FMA4(c2[7][1], a1.w, b1);
    }
  }

  if (n0 >= 2048) {
    const int nv0 = n0 - 2048;
#pragma unroll
    for (int a = 0; a < 8; a++) {
      *(float4*)&V[(size_t)(m0 + ty * 8 + a) * 1024 + nv0 + tx * 4]      = c2[a][0];
      *(float4*)&V[(size_t)(m0 + ty * 8 + a) * 1024 + nv0 + 64 + tx * 4] = c2[a][1];
    }
    return;
  }

  float* T = (n0 < 1024) ? qT : kT;
  const int nt0 = (n0 < 1024) ? n0 : (n0 - 1024);
  const int bB = m0 >> 10;
  const int i0 = m0 & 1023;
#pragma unroll
  for (int r = 0; r < 4; r++) {
    __syncthreads();
    if ((tx >> 3) == (r & 1)) {
      const int c0 = (tx & 7) * 4;
#pragma unroll
      for (int a = 0; a < 8; a++) {
        const int m = ty * 8 + a;
        float4 val = c2[a][r >> 1];
        tb[m * 32 + ((c0 + 0 + m) & 31)] = val.x;
        tb[m * 32 + ((c0 + 1 + m) & 31)] = val.y;
        tb[m * 32 + ((c0 + 2 + m) & 31)] = val.z;
        tb[m * 32 + ((c0 + 3 + m) & 31)] = val.w;
      }
    }
    __syncthreads();
    const int nl = t >> 3, mq = t & 7;
    float* Trow = T + (size_t)(bB * 1024 + nt0 + (r >> 1) * 64 + (r & 1) * 32 + nl) * 1024 + i0;
#pragma unroll
    for (int l = 0; l < 4; l++) {
      const int mb = (l * 8 + mq) * 4;
      float4 o;
      o.x = tb[(mb + 0) * 32 + ((nl + mb + 0) & 31)];
      o.y = tb[(mb + 1) * 32 + ((nl + mb + 1) & 31)];
      o.z = tb[(mb + 2) * 32 + ((nl + mb + 2) & 31)];
      o.w = tb[(mb + 3) * 32 + ((nl + mb + 3) & 31)];
      *(float4*)(Trow + mb) = o;
    }
  }
}

// ---------------------------------------------------------------------------
// K2a v5: no-LDS stats, float4 x float4 register tile. (unchanged)
// grid = b(4) x it(32 x 32i) x js(8 x 128j) = 1024. wave = 8i x 128j:
// lane: ih = l>>5 (i-quad), jg = l&31 (j-quad). acc[4][4]. Zero barriers.
// ---------------------------------------------------------------------------
__global__ __launch_bounds__(256) void attn_stats_v5(
    const float* __restrict__ qT, const float* __restrict__ kT,
    float* __restrict__ Mm, float* __restrict__ Ml)
{
  const int t  = threadIdx.x;
  const int bx = blockIdx.x;
  const int b  = bx >> 8;
  const int it = (bx >> 3) & 31;
  const int js = bx & 7;
  const int wv = t >> 6;
  const int l  = t & 63;
  const int ih = l >> 5;
  const int jg = l & 31;
  const int i0w = __builtin_amdgcn_readfirstlane(it * 32 + wv * 8);
  const int iq = i0w + ih * 4;
  const int jq = js * 128 + jg * 4;

  const float scale = 0.03125f;

  for (int h = 0; h < 16; h++) {
    const size_t base = (size_t)(b * 1024 + h * 64) * 1024;
    float4 acc[4];
#pragma unroll
    for (int ii = 0; ii < 4; ii++) acc[ii] = make_float4(0.f, 0.f, 0.f, 0.f);

#pragma unroll 4
    for (int d = 0; d < 64; d++) {
      const float4 qv = *(const float4*)(qT + base + (size_t)d * 1024 + iq);
      const float4 kv = *(const float4*)(kT + base + (size_t)d * 1024 + jq);
      FMA4(acc[0], qv.x, kv);
      FMA4(acc[1], qv.y, kv);
      FMA4(acc[2], qv.z, kv);
      FMA4(acc[3], qv.w, kv);
    }

#pragma unroll
    for (int ii = 0; ii < 4; ii++) {
      const float s0 = acc[ii].x * scale;
      const float s1 = acc[ii].y * scale;
      const float s2 = acc[ii].z * scale;
      const float s3 = acc[ii].w * scale;
      float mx = fmaxf(fmaxf(s0, s1), fmaxf(s2, s3));
      mx = fmaxf(mx, __shfl_xor(mx, 1));
      mx = fmaxf(mx, __shfl_xor(mx, 2));
      mx = fmaxf(mx, __shfl_xor(mx, 4));
      mx = fmaxf(mx, __shfl_xor(mx, 8));
      mx = fmaxf(mx, __shfl_xor(mx, 16));
      float ss = __expf(s0 - mx) + __expf(s1 - mx) +
                 __expf(s2 - mx) + __expf(s3 - mx);
      ss += __shfl_xor(ss, 1);
      ss += __shfl_xor(ss, 2);
      ss += __shfl_xor(ss, 4);
      ss += __shfl_xor(ss, 8);
      ss += __shfl_xor(ss, 16);
      if (jg == ii) {
        const int idx = (((b * 16 + h) * 1024 + iq + ii) << 3) + js;
        Mm[idx] = mx;
        Ml[idx] = ss;
      }
    }
  }
}

// packed key: monotone(float) << 32 | (1023 - j); atomicMax == (>, tie: min j)
__device__ inline unsigned long long mkkey(float v, int j) {
  unsigned u = __float_as_uint(v);
  u = (u & 0x80000000u) ? ~u : (u | 0x80000000u);
  return ((unsigned long long)u << 32) | (unsigned)(1023 - j);
}

// ---------------------------------------------------------------------------
// K2b v9: grid = b(4) x it(64 x 16i) x js(32 x 32j) = 8192 blocks, 256 thr.
// Tile 16i x 32j x 16h. LDS: ptile 32*271 f + 512 red = 36.7KB ->
// 4 blocks/CU x 4 waves = 16 waves/CU (4/SIMD) — matches natural VGPR=128.
// Dot: 2 rounds; per round a wave covers 16i x 32j x 2h.
//   lane: hp = l&1 (head pair), jg = (l>>1)&7 (8 x 4j), ig = l>>4 (4 x 4i);
//   per-lane 4i x 4j for h = wv*4 + hr*2 + hp; float4 q x float4 k
//   (2 VMEM / 16 FMA — v5's verified economy).
// p -> ptile[j*271 + iL*17 + hrot], hrot = (h + j>>2)&15 (v5 rotation).
// Mix: v5 verbatim (i2=t>>4, g=(t>>2)&3, hq=t&3), jj loop over 8 (32 j),
// merge xor 4,8; packed atomicMax. NO arg2 on launch_bounds (spill tripwire).
// ---------------------------------------------------------------------------
__global__ __launch_bounds__(256) void attn_select_v9(
    const float* __restrict__ qT, const float* __restrict__ kT,
    const float* __restrict__ Mm, const float* __restrict__ Ml,
    const float* __restrict__ Wt, const float* __restrict__ ln_g,
    const float* __restrict__ ln_b, unsigned long long* __restrict__ HiKey)
{
  __shared__ __align__(16) float smem[32 * 271 + 512];
  float* ptile = smem;                 // j*271 + i_local*17 + hrot
  float* mred  = smem + 32 * 271;      // [h*16 + i_local]
  float* rred  = mred + 256;

  const int t  = threadIdx.x;
  const int bx = blockIdx.x;
  const int b  = bx >> 11;
  const int it = (bx >> 5) & 63;
  const int js = bx & 31;
  const int i0 = it << 4;
  const int j0 = js << 5;

  const float scale = 0.03125f;

  // prologue: merge-8 slice stats (t == h*16 + i_local)
  {
    const int base = (((b * 16 + (t >> 4)) * 1024 + i0 + (t & 15)) << 3);
    const float4 ma = *(const float4*)&Mm[base];
    const float4 mb = *(const float4*)&Mm[base + 4];
    const float4 la = *(const float4*)&Ml[base];
    const float4 lb = *(const float4*)&Ml[base + 4];
    float M = fmaxf(fmaxf(fmaxf(ma.x, ma.y), fmaxf(ma.z, ma.w)),
                    fmaxf(fmaxf(mb.x, mb.y), fmaxf(mb.z, mb.w)));
    float L = la.x * __expf(ma.x - M) + la.y * __expf(ma.y - M) +
              la.z * __expf(ma.z - M) + la.w * __expf(ma.w - M) +
              lb.x * __expf(mb.x - M) + lb.y * __expf(mb.y - M) +
              lb.z * __expf(mb.z - M) + lb.w * __expf(mb.w - M);
    mred[t] = M;
    rred[t] = 1.0f / L;
  }
  __syncthreads();

  // ---- dot phase: 2 rounds x (16i x 32j x 2h) per wave ----
  const int wv = t >> 6;
  const int l  = t & 63;
  const int hp = l & 1;
  const int jg = (l >> 1) & 7;
  const int ig = l >> 4;
  const int iq = i0 + ig * 4;
  const int jcol = j0 + jg * 4;

#pragma unroll
  for (int hr = 0; hr < 2; hr++) {
    const int h = wv * 4 + hr * 2 + hp;
    const size_t base = (size_t)(b * 1024 + h * 64) * 1024;
    float4 acc[4];
#pragma unroll
    for (int ii = 0; ii < 4; ii++) acc[ii] = make_float4(0.f, 0.f, 0.f, 0.f);

#pragma unroll 4
    for (int d = 0; d < 64; d++) {
      const float4 qv = *(const float4*)(qT + base + (size_t)d * 1024 + iq);
      const float4 kv = *(const float4*)(kT + base + (size_t)d * 1024 + jcol);
      FMA4(acc[0], qv.x, kv);
      FMA4(acc[1], qv.y, kv);
      FMA4(acc[2], qv.z, kv);
      FMA4(acc[3], qv.w, kv);
    }

    const int hrot = (h + jg) & 15;   // j>>2 == jg for this lane's 4 j
#pragma unroll
    for (int ii = 0; ii < 4; ii++) {
      const int iL = ig * 4 + ii;
      const float m = mred[h * 16 + iL];
      const float r = rred[h * 16 + iL];
      const float a4[4] = {acc[ii].x, acc[ii].y, acc[ii].z, acc[ii].w};
#pragma unroll
      for (int jj = 0; jj < 4; jj++) {
        const int j = jg * 4 + jj;
        const float p = __expf(a4[jj] * scale - m) * r;
        ptile[j * 271 + iL * 17 + hrot] = p;
      }
    }
  }
  __syncthreads();

  // ---- mix phase: i2 = t>>4 (16 i), g = (t>>2)&3 (4 x 8j), hq = t&3 ----
  const int i2 = t >> 4;
  const int g  = (t >> 2) & 3;
  const int hq = t & 3;

  float wtr[4][16], gr[4], br[4];
#pragma unroll
  for (int a = 0; a < 4; a++) {
#pragma unroll
    for (int h2 = 0; h2 < 16; h2++) wtr[a][h2] = Wt[(hq * 4 + a) * 16 + h2];
    gr[a] = ln_g[hq * 4 + a];
    br[a] = ln_b[hq * 4 + a];
  }
  float bv[4]; int bix[4];
#pragma unroll
  for (int a = 0; a < 4; a++) { bv[a] = -1e30f; bix[a] = 0; }

#pragma unroll
  for (int jj = 0; jj < 8; jj++) {
    const int j = g * 8 + jj;
    const int jr = j >> 2;
    float pv[16];
#pragma unroll
    for (int h2 = 0; h2 < 16; h2++)
      pv[h2] = ptile[j * 271 + i2 * 17 + ((h2 + jr) & 15)];
    float mix[4];
#pragma unroll
    for (int a = 0; a < 4; a++) {
      float s0 = 0.f;
#pragma unroll
      for (int h2 = 0; h2 < 16; h2++) s0 = fmaf(pv[h2], wtr[a][h2], s0);
      mix[a] = s0;
    }
    float s1 = mix[0] + mix[1] + mix[2] + mix[3];
    s1 += __shfl_xor(s1, 1);
    s1 += __shfl_xor(s1, 2);
    const float mu = s1 * 0.0625f;
    float s2 = 0.f;
#pragma unroll
    for (int a = 0; a < 4; a++) { const float dd = mix[a] - mu; s2 = fmaf(dd, dd, s2); }
    s2 += __shfl_xor(s2, 1);
    s2 += __shfl_xor(s2, 2);
    const float rstd = rsqrtf(s2 * 0.0625f + 1e-5f);
    const int jg2 = j0 + j;
#pragma unroll
    for (int a = 0; a < 4; a++) {
      const float nv = (mix[a] - mu) * rstd * gr[a] + br[a];
      if (nv > bv[a]) { bv[a] = nv; bix[a] = jg2; }
    }
  }

  // merge over the 4 g-lanes (ties -> smaller j), then one atomic per (a,i)
#pragma unroll
  for (int a = 0; a < 4; a++) {
    float v = bv[a]; int ix = bix[a];
    {
      const float ov = __shfl_xor(v, 4);
      const int oi = __shfl_xor(ix, 4);
      if (ov > v || (ov == v && oi < ix)) { v = ov; ix = oi; }
    }
    {
      const float ov = __shfl_xor(v, 8);
      const int oi = __shfl_xor(ix, 8);
      if (ov > v || (ov == v && oi < ix)) { v = ov; ix = oi; }
    }
    bv[a] = v; bix[a] = ix;
  }

  if (g == 0) {
#pragma unroll
    for (int a = 0; a < 4; a++) {
      const int cell = (b * 16 + hq * 4 + a) * 1024 + i0 + i2;
      atomicMax(&HiKey[cell], mkkey(bv[a], bix[a]));
    }
  }
}

// ---------------------------------------------------------------------------
// K2c: decode key -> gather V rows (unchanged).
// ---------------------------------------------------------------------------
__global__ __launch_bounds__(256) void gather_v4(
    const unsigned long long* __restrict__ HiKey, const float* __restrict__ V,
    float* __restrict__ out)
{
  const int t  = threadIdx.x;
  const int bx = blockIdx.x;
  const int b  = bx >> 6;
  const int it = bx & 63;
  const int i2 = t >> 4;
  const int h  = t & 15;

  const unsigned long long key = HiKey[(b * 16 + h) * 1024 + it * 16 + i2];
  const int j = 1023 - (int)(unsigned)(key & 0xFFFFFFFFull);

  const float* vs = V + (size_t)(b * 1024 + j) * 1024 + h * 64;
  float* dst = out + (size_t)(b * 1024 + it * 16 + i2) * 1024 + h * 64;
#pragma unroll
  for (int w = 0; w < 16; w++)
    *(float4*)(dst + w * 4) = *(const float4*)(vs + w * 4);
}

extern "C" void kernel_launch(void* const* d_in, const int* in_sizes, int n_in,
                              void* d_out, int out_size, void* d_ws, size_t ws_size,
                              hipStream_t stream) {
  const float* x   = (const float*)d_in[0];
  const float* Wq  = (const float*)d_in[1];
  const float* Wkv = (const float*)d_in[2];
  const float* Wt  = (const float*)d_in[3];
  const float* lng = (const float*)d_in[4];
  const float* lnb = (const float*)d_in[5];
  float* out = (float*)d_out;
  float* ws  = (float*)d_ws;                          // 52.5 MB used
  float* qT = ws;                                     // 4M f
  float* kT = ws + (size_t)4 * 1024 * 1024;           // 4M f
  float* V  = ws + (size_t)8 * 1024 * 1024;           // 4M f
  float* Mm = ws + (size_t)12 * 1024 * 1024;          // 512K f
  float* Ml = Mm + 524288;                            // 512K f
  unsigned long long* HiKey =
      (unsigned long long*)(ws + (size_t)13 * 1024 * 1024);  // 64K x 8B

  hipLaunchKernelGGL(qkv_gemm, dim3(24, 32), dim3(256), 0, stream,
                     x, Wq, Wkv, qT, kT, V);
  hipMemsetAsync(HiKey, 0, (size_t)65536 * 8, stream);
  hipLaunchKernelGGL(attn_stats_v5, dim3(1024), dim3(256), 0, stream,
                     qT, kT, Mm, Ml);
  hipLaunchKernelGGL(attn_select_v9, dim3(8192), dim3(256), 0, stream,
                     qT, kT, Mm, Ml, Wt, lng, lnb, HiKey);
  hipLaunchKernelGGL(gather_v4, dim3(256), dim3(256), 0, stream,
                     HiKey, V, out);
}

// Round 6
// 1155.108 us; speedup vs baseline: 1.1164x; 1.0077x over previous
//
#include <hip/hip_runtime.h>

// Relation_5841155522972 — talking-heads attention, straight-through hard select.
// out[b,i,h*64+d] = v[b, argmax_j n[b,h,i,j], h*64+d],
// n = LayerNorm_h( softmax_j(QK^T/32) mixed by Wt ).
//
// R11: occupancy tier model (5 measured points, R6-R10): waves/SIMD =
// floor(256/VGPR) on this toolchain -> VGPR in (64,128] gives only 2
// waves/SIMD. 16 waves/CU therefore REQUIRES VGPR<=64 spill-free. v8 proved
// residency (45.6% at 64 VGPR + 36.8KB LDS) but spilled on wtr[4][16].
// v10 = v9 with a register-light mix: each thread owns 2 output heads
// (wtr[2][16]=32 regs) x 16 j; LN reduce over the 8 h-pair lanes
// (shfl_xor 1,2,4); argmax merge across g halves (xor 8). Working set ~56
// VGPR. __launch_bounds__(256,4) -> 64-VGPR cap (verified exact on R6/R8).
// Dot phase / prologue / rotation layout / other kernels: identical to v9.
//  K1  qkv_gemm        : unchanged fp32 GEMM (qT/kT transposed, V straight).
//  K2a attn_stats_v5   : unchanged (no-LDS, zero-barrier).
//  K2b attn_select_v10 : 36KB tile, 64-VGPR mix, 16 waves/CU target.
//  K2c gather_v4       : unchanged.
// ws: 52.5 MB.

#define FMA4(cc, av, bv) \
  cc.x = fmaf(av, bv.x, cc.x); cc.y = fmaf(av, bv.y, cc.y); \
  cc.z = fmaf(av, bv.z, cc.z); cc.w = fmaf(av, bv.w, cc.w);

__global__ __launch_bounds__(256) void qkv_gemm(
    const float* __restrict__ X, const float* __restrict__ Wq,
    const float* __restrict__ Wkv, float* __restrict__ qT,
    float* __restrict__ kT, float* __restrict__ V)
{
  __shared__ __align__(16) float As[16 * 132];
  __shared__ __align__(16) float Bs[16 * 132];
  __shared__ __align__(16) float tb[128 * 32];

  const int t  = threadIdx.x;
  const int bn = blockIdx.x;
  const int bm = blockIdx.y;
  const int m0 = bm * 128, n0 = bn * 128;
  const int ty = t >> 4, tx = t & 15;

  const float* Wbase = (n0 < 1024) ? Wq : Wkv;
  const int nw0 = (n0 < 1024) ? n0 : (n0 - 1024);

  float4 c2[8][2];
#pragma unroll
  for (int a = 0; a < 8; a++) {
    c2[a][0] = make_float4(0.f, 0.f, 0.f, 0.f);
    c2[a][1] = make_float4(0.f, 0.f, 0.f, 0.f);
  }

  const int lr = t >> 1;
  const int lh = t & 1;

  const float4* As4 = (const float4*)As;
  const float4* Bs4 = (const float4*)Bs;

  for (int kb = 0; kb < 64; kb++) {
    const int k0 = kb * 16;
    __syncthreads();
#pragma unroll
    for (int s = 0; s < 2; s++) {
      const int kk = lh * 8 + s * 4;
      float4 av = *(const float4*)&X[(size_t)(m0 + lr) * 1024 + k0 + kk];
      float4 bv = *(const float4*)&Wbase[(size_t)(nw0 + lr) * 1024 + k0 + kk];
      As[(kk + 0) * 132 + lr] = av.x;
      As[(kk + 1) * 132 + lr] = av.y;
      As[(kk + 2) * 132 + lr] = av.z;
      As[(kk + 3) * 132 + lr] = av.w;
      Bs[(kk + 0) * 132 + lr] = bv.x;
      Bs[(kk + 1) * 132 + lr] = bv.y;
      Bs[(kk + 2) * 132 + lr] = bv.z;
      Bs[(kk + 3) * 132 + lr] = bv.w;
    }
    __syncthreads();
#pragma unroll
    for (int kk = 0; kk < 16; kk++) {
      float4 a0 = As4[kk * 33 + ty * 2];
      float4 a1 = As4[kk * 33 + ty * 2 + 1];
      float4 b0 = Bs4[kk * 33 + tx];
      float4 b1 = Bs4[kk * 33 + 16 + tx];
      FMA4(c2[0][0], a0.x, b0); FMA4(c2[0][1], a0.x, b1);
      FMA4(c2[1][0], a0.y, b0); FMA4(c2[1][1], a0.y, b1);
      FMA4(c2[2][0], a0.z, b0); FMA4(c2[2][1], a0.z, b1);
      FMA4(c2[3][0], a0.w, b0); FMA4(c2[3][1], a0.w, b1);
      FMA4(c2[4][0], a1.x, b0); FMA4(c2[4][1], a1.x, b1);
      FMA4(c2[5][0], a1.y, b0); FMA4(c2[5][1], a1.y, b1);
      FMA4(c2[6][0], a1.z, b0); FMA4(c2[6][1], a1.z, b1);
      FMA4(c2[7][0], a1.w, b0); FMA4(c2[7][1], a1.w, b1);
    }
  }

  if (n0 >= 2048) {
    const int nv0 = n0 - 2048;
#pragma unroll
    for (int a = 0; a < 8; a++) {
      *(float4*)&V[(size_t)(m0 + ty * 8 + a) * 1024 + nv0 + tx * 4]      = c2[a][0];
      *(float4*)&V[(size_t)(m0 + ty * 8 + a) * 1024 + nv0 + 64 + tx * 4] = c2[a][1];
    }
    return;
  }

  float* T = (n0 < 1024) ? qT : kT;
  const int nt0 = (n0 < 1024) ? n0 : (n0 - 1024);
  const int bB = m0 >> 10;
  const int i0 = m0 & 1023;
#pragma unroll
  for (int r = 0; r < 4; r++) {
    __syncthreads();
    if ((tx >> 3) == (r & 1)) {
      const int c0 = (tx & 7) * 4;
#pragma unroll
      for (int a = 0; a < 8; a++) {
        const int m = ty * 8 + a;
        float4 val = c2[a][r >> 1];
        tb[m * 32 + ((c0 + 0 + m) & 31)] = val.x;
        tb[m * 32 + ((c0 + 1 + m) & 31)] = val.y;
        tb[m * 32 + ((c0 + 2 + m) & 31)] = val.z;
        tb[m * 32 + ((c0 + 3 + m) & 31)] = val.w;
      }
    }
    __syncthreads();
    const int nl = t >> 3, mq = t & 7;
    float* Trow = T + (size_t)(bB * 1024 + nt0 + (r >> 1) * 64 + (r & 1) * 32 + nl) * 1024 + i0;
#pragma unroll
    for (int l = 0; l < 4; l++) {
      const int mb = (l * 8 + mq) * 4;
      float4 o;
      o.x = tb[(mb + 0) * 32 + ((nl + mb + 0) & 31)];
      o.y = tb[(mb + 1) * 32 + ((nl + mb + 1) & 31)];
      o.z = tb[(mb + 2) * 32 + ((nl + mb + 2) & 31)];
      o.w = tb[(mb + 3) * 32 + ((nl + mb + 3) & 31)];
      *(float4*)(Trow + mb) = o;
    }
  }
}

// ---------------------------------------------------------------------------
// K2a v5: no-LDS stats, float4 x float4 register tile. (unchanged)
// ---------------------------------------------------------------------------
__global__ __launch_bounds__(256) void attn_stats_v5(
    const float* __restrict__ qT, const float* __restrict__ kT,
    float* __restrict__ Mm, float* __restrict__ Ml)
{
  const int t  = threadIdx.x;
  const int bx = blockIdx.x;
  const int b  = bx >> 8;
  const int it = (bx >> 3) & 31;
  const int js = bx & 7;
  const int wv = t >> 6;
  const int l  = t & 63;
  const int ih = l >> 5;
  const int jg = l & 31;
  const int i0w = __builtin_amdgcn_readfirstlane(it * 32 + wv * 8);
  const int iq = i0w + ih * 4;
  const int jq = js * 128 + jg * 4;

  const float scale = 0.03125f;

  for (int h = 0; h < 16; h++) {
    const size_t base = (size_t)(b * 1024 + h * 64) * 1024;
    float4 acc[4];
#pragma unroll
    for (int ii = 0; ii < 4; ii++) acc[ii] = make_float4(0.f, 0.f, 0.f, 0.f);

#pragma unroll 4
    for (int d = 0; d < 64; d++) {
      const float4 qv = *(const float4*)(qT + base + (size_t)d * 1024 + iq);
      const float4 kv = *(const float4*)(kT + base + (size_t)d * 1024 + jq);
      FMA4(acc[0], qv.x, kv);
      FMA4(acc[1], qv.y, kv);
      FMA4(acc[2], qv.z, kv);
      FMA4(acc[3], qv.w, kv);
    }

#pragma unroll
    for (int ii = 0; ii < 4; ii++) {
      const float s0 = acc[ii].x * scale;
      const float s1 = acc[ii].y * scale;
      const float s2 = acc[ii].z * scale;
      const float s3 = acc[ii].w * scale;
      float mx = fmaxf(fmaxf(s0, s1), fmaxf(s2, s3));
      mx = fmaxf(mx, __shfl_xor(mx, 1));
      mx = fmaxf(mx, __shfl_xor(mx, 2));
      mx = fmaxf(mx, __shfl_xor(mx, 4));
      mx = fmaxf(mx, __shfl_xor(mx, 8));
      mx = fmaxf(mx, __shfl_xor(mx, 16));
      float ss = __expf(s0 - mx) + __expf(s1 - mx) +
                 __expf(s2 - mx) + __expf(s3 - mx);
      ss += __shfl_xor(ss, 1);
      ss += __shfl_xor(ss, 2);
      ss += __shfl_xor(ss, 4);
      ss += __shfl_xor(ss, 8);
      ss += __shfl_xor(ss, 16);
      if (jg == ii) {
        const int idx = (((b * 16 + h) * 1024 + iq + ii) << 3) + js;
        Mm[idx] = mx;
        Ml[idx] = ss;
      }
    }
  }
}

// packed key: monotone(float) << 32 | (1023 - j); atomicMax == (>, tie: min j)
__device__ inline unsigned long long mkkey(float v, int j) {
  unsigned u = __float_as_uint(v);
  u = (u & 0x80000000u) ? ~u : (u | 0x80000000u);
  return ((unsigned long long)u << 32) | (unsigned)(1023 - j);
}

// ---------------------------------------------------------------------------
// K2b v10: grid = b(4) x it(64 x 16i) x js(32 x 32j) = 8192 blocks, 256 thr.
// Tile 16i x 32j x 16h, LDS 36.8KB. __launch_bounds__(256,4) -> 64-VGPR cap
// (empirically exact, R6/R8); working set now fits:
//  - dot: identical to v9 (2 rounds x 2h/wave; lane 4i x 4j; acc[4] float4).
//  - mix: thread = (i2: t>>4, g: (t>>3)&1 two 16j halves, hq2: t&7 h-pair).
//    wtr[2][16] = 32 regs; per j: 16 pv LDS reads amortized over 2 h_out,
//    32 FMA; LN over 16 h via pair-sum + shfl_xor 1,2,4 (8 h-pair lanes);
//    argmax merged across g via xor 8; 2 atomics per g==0 thread (256/block).
// Rotation layout unchanged (write hrot=(h+j>>2)&15; read (h2+jr)&15).
// ---------------------------------------------------------------------------
__global__ __launch_bounds__(256, 4) void attn_select_v10(
    const float* __restrict__ qT, const float* __restrict__ kT,
    const float* __restrict__ Mm, const float* __restrict__ Ml,
    const float* __restrict__ Wt, const float* __restrict__ ln_g,
    const float* __restrict__ ln_b, unsigned long long* __restrict__ HiKey)
{
  __shared__ __align__(16) float smem[32 * 271 + 512];
  float* ptile = smem;                 // j*271 + i_local*17 + hrot
  float* mred  = smem + 32 * 271;      // [h*16 + i_local]
  float* rred  = mred + 256;

  const int t  = threadIdx.x;
  const int bx = blockIdx.x;
  const int b  = bx >> 11;
  const int it = (bx >> 5) & 63;
  const int js = bx & 31;
  const int i0 = it << 4;
  const int j0 = js << 5;

  const float scale = 0.03125f;

  // prologue: merge-8 slice stats (t == h*16 + i_local)
  {
    const int base = (((b * 16 + (t >> 4)) * 1024 + i0 + (t & 15)) << 3);
    const float4 ma = *(const float4*)&Mm[base];
    const float4 mb = *(const float4*)&Mm[base + 4];
    const float4 la = *(const float4*)&Ml[base];
    const float4 lb = *(const float4*)&Ml[base + 4];
    float M = fmaxf(fmaxf(fmaxf(ma.x, ma.y), fmaxf(ma.z, ma.w)),
                    fmaxf(fmaxf(mb.x, mb.y), fmaxf(mb.z, mb.w)));
    float L = la.x * __expf(ma.x - M) + la.y * __expf(ma.y - M) +
              la.z * __expf(ma.z - M) + la.w * __expf(ma.w - M) +
              lb.x * __expf(mb.x - M) + lb.y * __expf(mb.y - M) +
              lb.z * __expf(mb.z - M) + lb.w * __expf(mb.w - M);
    mred[t] = M;
    rred[t] = 1.0f / L;
  }
  __syncthreads();

  // ---- dot phase: 2 rounds x (16i x 32j x 2h) per wave (identical to v9) ----
  const int wv = t >> 6;
  const int l  = t & 63;
  const int hp = l & 1;
  const int jg = (l >> 1) & 7;
  const int ig = l >> 4;
  const int iq = i0 + ig * 4;
  const int jcol = j0 + jg * 4;

#pragma unroll
  for (int hr = 0; hr < 2; hr++) {
    const int h = wv * 4 + hr * 2 + hp;
    const size_t base = (size_t)(b * 1024 + h * 64) * 1024;
    float4 acc[4];
#pragma unroll
    for (int ii = 0; ii < 4; ii++) acc[ii] = make_float4(0.f, 0.f, 0.f, 0.f);

#pragma unroll 4
    for (int d = 0; d < 64; d++) {
      const float4 qv = *(const float4*)(qT + base + (size_t)d * 1024 + iq);
      const float4 kv = *(const float4*)(kT + base + (size_t)d * 1024 + jcol);
      FMA4(acc[0], qv.x, kv);
      FMA4(acc[1], qv.y, kv);
      FMA4(acc[2], qv.z, kv);
      FMA4(acc[3], qv.w, kv);
    }

    const int hrot = (h + jg) & 15;   // j>>2 == jg for this lane's 4 j
#pragma unroll
    for (int ii = 0; ii < 4; ii++) {
      const int iL = ig * 4 + ii;
      const float m = mred[h * 16 + iL];
      const float r = rred[h * 16 + iL];
      const float a4[4] = {acc[ii].x, acc[ii].y, acc[ii].z, acc[ii].w};
#pragma unroll
      for (int jj = 0; jj < 4; jj++) {
        const int j = jg * 4 + jj;
        const float p = __expf(a4[jj] * scale - m) * r;
        ptile[j * 271 + iL * 17 + hrot] = p;
      }
    }
  }
  __syncthreads();

  // ---- mix phase: i2 = t>>4 (16 i), g = (t>>3)&1 (16j half), hq2 = t&7 ----
  const int i2  = t >> 4;
  const int g   = (t >> 3) & 1;
  const int hq2 = t & 7;

  float wtr[2][16], gr[2], br[2];
#pragma unroll
  for (int c = 0; c < 2; c++) {
#pragma unroll
    for (int h2 = 0; h2 < 16; h2++) wtr[c][h2] = Wt[(hq2 * 2 + c) * 16 + h2];
    gr[c] = ln_g[hq2 * 2 + c];
    br[c] = ln_b[hq2 * 2 + c];
  }
  float bv[2]; int bix[2];
  bv[0] = bv[1] = -1e30f; bix[0] = bix[1] = 0;

#pragma unroll 4
  for (int jj = 0; jj < 16; jj++) {
    const int j = g * 16 + jj;
    const int jr = j >> 2;
    float m0 = 0.f, m1 = 0.f;
#pragma unroll
    for (int h2 = 0; h2 < 16; h2++) {
      const float p = ptile[j * 271 + i2 * 17 + ((h2 + jr) & 15)];
      m0 = fmaf(p, wtr[0][h2], m0);
      m1 = fmaf(p, wtr[1][h2], m1);
    }
    // LayerNorm over 16 heads = 8 h-pair lanes x 2 local
    float s1 = m0 + m1;
    s1 += __shfl_xor(s1, 1);
    s1 += __shfl_xor(s1, 2);
    s1 += __shfl_xor(s1, 4);
    const float mu = s1 * 0.0625f;
    const float d0 = m0 - mu, d1 = m1 - mu;
    float s2 = fmaf(d0, d0, d1 * d1);
    s2 += __shfl_xor(s2, 1);
    s2 += __shfl_xor(s2, 2);
    s2 += __shfl_xor(s2, 4);
    const float rstd = rsqrtf(s2 * 0.0625f + 1e-5f);
    const int jg2 = j0 + j;
    {
      const float nv = d0 * rstd * gr[0] + br[0];
      if (nv > bv[0]) { bv[0] = nv; bix[0] = jg2; }
    }
    {
      const float nv = d1 * rstd * gr[1] + br[1];
      if (nv > bv[1]) { bv[1] = nv; bix[1] = jg2; }
    }
  }

  // merge across the two g halves (xor 8); ties -> smaller j
#pragma unroll
  for (int c = 0; c < 2; c++) {
    float v = bv[c]; int ix = bix[c];
    const float ov = __shfl_xor(v, 8);
    const int oi = __shfl_xor(ix, 8);
    if (ov > v || (ov == v && oi < ix)) { v = ov; ix = oi; }
    bv[c] = v; bix[c] = ix;
  }

  if (g == 0) {
#pragma unroll
    for (int c = 0; c < 2; c++) {
      const int cell = (b * 16 + hq2 * 2 + c) * 1024 + i0 + i2;
      atomicMax(&HiKey[cell], mkkey(bv[c], bix[c]));
    }
  }
}

// ---------------------------------------------------------------------------
// K2c: decode key -> gather V rows (unchanged).
// ---------------------------------------------------------------------------
__global__ __launch_bounds__(256) void gather_v4(
    const unsigned long long* __restrict__ HiKey, const float* __restrict__ V,
    float* __restrict__ out)
{
  const int t  = threadIdx.x;
  const int bx = blockIdx.x;
  const int b  = bx >> 6;
  const int it = bx & 63;
  const int i2 = t >> 4;
  const int h  = t & 15;

  const unsigned long long key = HiKey[(b * 16 + h) * 1024 + it * 16 + i2];
  const int j = 1023 - (int)(unsigned)(key & 0xFFFFFFFFull);

  const float* vs = V + (size_t)(b * 1024 + j) * 1024 + h * 64;
  float* dst = out + (size_t)(b * 1024 + it * 16 + i2) * 1024 + h * 64;
#pragma unroll
  for (int w = 0; w < 16; w++)
    *(float4*)(dst + w * 4) = *(const float4*)(vs + w * 4);
}

extern "C" void kernel_launch(void* const* d_in, const int* in_sizes, int n_in,
                              void* d_out, int out_size, void* d_ws, size_t ws_size,
                              hipStream_t stream) {
  const float* x   = (const float*)d_in[0];
  const float* Wq  = (const float*)d_in[1];
  const float* Wkv = (const float*)d_in[2];
  const float* Wt  = (const float*)d_in[3];
  const float* lng = (const float*)d_in[4];
  const float* lnb = (const float*)d_in[5];
  float* out = (float*)d_out;
  float* ws  = (float*)d_ws;                          // 52.5 MB used
  float* qT = ws;                                     // 4M f
  float* kT = ws + (size_t)4 * 1024 * 1024;           // 4M f
  float* V  = ws + (size_t)8 * 1024 * 1024;           // 4M f
  float* Mm = ws + (size_t)12 * 1024 * 1024;          // 512K f
  float* Ml = Mm + 524288;                            // 512K f
  unsigned long long* HiKey =
      (unsigned long long*)(ws + (size_t)13 * 1024 * 1024);  // 64K x 8B

  hipLaunchKernelGGL(qkv_gemm, dim3(24, 32), dim3(256), 0, stream,
                     x, Wq, Wkv, qT, kT, V);
  hipMemsetAsync(HiKey, 0, (size_t)65536 * 8, stream);
  hipLaunchKernelGGL(attn_stats_v5, dim3(1024), dim3(256), 0, stream,
                     qT, kT, Mm, Ml);
  hipLaunchKernelGGL(attn_select_v10, dim3(8192), dim3(256), 0, stream,
                     qT, kT, Mm, Ml, Wt, lng, lnb, HiKey);
  hipLaunchKernelGGL(gather_v4, dim3(256), dim3(256), 0, stream,
                     HiKey, V, out);
}

// Round 7
// 978.900 us; speedup vs baseline: 1.3174x; 1.1800x over previous
//
#include <hip/hip_runtime.h>

// Relation_5841155522972 — talking-heads attention, straight-through hard select.
// out[b,i,h*64+d] = v[b, argmax_j n[b,h,i,j], h*64+d],
// n = LayerNorm_h( softmax_j(QK^T/32) mixed by Wt ).
//
// R12: eliminate the redundant QK^T recompute. Occupancy axis is closed
// (R6-R11: VGPR pool ~256/SIMD-slot; this working set wants 100-128 VGPR ->
// 2 waves/SIMD, and the 64-VGPR tier wrecks ILP: v10 slower than v5 despite
// 2x occupancy). Instead: attn_stats already computes exp(s - m_slice) for
// its row sums — store it (E, fp32, 256 MB ws) and make select a streamed
// E-read: p = E * f, f = exp(m_slice - M)/L per (h,i,block-slice), computed
// in the existing prologue. Mix/LN/argmax = v5 verbatim (fastest measured).
// ws capacity guard: if ws_size < 312 MB, fall back to exact v5 pipeline.
//  K1   qkv_gemm        : unchanged fp32 GEMM.
//  K2a  attn_stats_v6   : v5 + E-store (fallback: attn_stats_v5).
//  K2b  attn_select_v11 : no-dot select, E-stream + v5 mix (fallback: v5).
//  K2c  gather_v4       : unchanged.
// ws: 52.5 MB (A-path) / 312 MB (B-path).

#define FMA4(cc, av, bv) \
  cc.x = fmaf(av, bv.x, cc.x); cc.y = fmaf(av, bv.y, cc.y); \
  cc.z = fmaf(av, bv.z, cc.z); cc.w = fmaf(av, bv.w, cc.w);

__global__ __launch_bounds__(256) void qkv_gemm(
    const float* __restrict__ X, const float* __restrict__ Wq,
    const float* __restrict__ Wkv, float* __restrict__ qT,
    float* __restrict__ kT, float* __restrict__ V)
{
  __shared__ __align__(16) float As[16 * 132];
  __shared__ __align__(16) float Bs[16 * 132];
  __shared__ __align__(16) float tb[128 * 32];

  const int t  = threadIdx.x;
  const int bn = blockIdx.x;
  const int bm = blockIdx.y;
  const int m0 = bm * 128, n0 = bn * 128;
  const int ty = t >> 4, tx = t & 15;

  const float* Wbase = (n0 < 1024) ? Wq : Wkv;
  const int nw0 = (n0 < 1024) ? n0 : (n0 - 1024);

  float4 c2[8][2];
#pragma unroll
  for (int a = 0; a < 8; a++) {
    c2[a][0] = make_float4(0.f, 0.f, 0.f, 0.f);
    c2[a][1] = make_float4(0.f, 0.f, 0.f, 0.f);
  }

  const int lr = t >> 1;
  const int lh = t & 1;

  const float4* As4 = (const float4*)As;
  const float4* Bs4 = (const float4*)Bs;

  for (int kb = 0; kb < 64; kb++) {
    const int k0 = kb * 16;
    __syncthreads();
#pragma unroll
    for (int s = 0; s < 2; s++) {
      const int kk = lh * 8 + s * 4;
      float4 av = *(const float4*)&X[(size_t)(m0 + lr) * 1024 + k0 + kk];
      float4 bv = *(const float4*)&Wbase[(size_t)(nw0 + lr) * 1024 + k0 + kk];
      As[(kk + 0) * 132 + lr] = av.x;
      As[(kk + 1) * 132 + lr] = av.y;
      As[(kk + 2) * 132 + lr] = av.z;
      As[(kk + 3) * 132 + lr] = av.w;
      Bs[(kk + 0) * 132 + lr] = bv.x;
      Bs[(kk + 1) * 132 + lr] = bv.y;
      Bs[(kk + 2) * 132 + lr] = bv.z;
      Bs[(kk + 3) * 132 + lr] = bv.w;
    }
    __syncthreads();
#pragma unroll
    for (int kk = 0; kk < 16; kk++) {
      float4 a0 = As4[kk * 33 + ty * 2];
      float4 a1 = As4[kk * 33 + ty * 2 + 1];
      float4 b0 = Bs4[kk * 33 + tx];
      float4 b1 = Bs4[kk * 33 + 16 + tx];
      FMA4(c2[0][0], a0.x, b0); FMA4(c2[0][1], a0.x, b1);
      FMA4(c2[1][0], a0.y, b0); FMA4(c2[1][1], a0.y, b1);
      FMA4(c2[2][0], a0.z, b0); FMA4(c2[2][1], a0.z, b1);
      FMA4(c2[3][0], a0.w, b0); FMA4(c2[3][1], a0.w, b1);
      FMA4(c2[4][0], a1.x, b0); FMA4(c2[4][1], a1.x, b1);
      FMA4(c2[5][0], a1.y, b0); FMA4(c2[5][1], a1.y, b1);
      FMA4(c2[6][0], a1.z, b0); FMA4(c2[6][1], a1.z, b1);
      FMA4(c2[7][0], a1.w, b0); FMA4(c2[7][1], a1.w, b1);
    }
  }

  if (n0 >= 2048) {
    const int nv0 = n0 - 2048;
#pragma unroll
    for (int a = 0; a < 8; a++) {
      *(float4*)&V[(size_t)(m0 + ty * 8 + a) * 1024 + nv0 + tx * 4]      = c2[a][0];
      *(float4*)&V[(size_t)(m0 + ty * 8 + a) * 1024 + nv0 + 64 + tx * 4] = c2[a][1];
    }
    return;
  }

  float* T = (n0 < 1024) ? qT : kT;
  const int nt0 = (n0 < 1024) ? n0 : (n0 - 1024);
  const int bB = m0 >> 10;
  const int i0 = m0 & 1023;
#pragma unroll
  for (int r = 0; r < 4; r++) {
    __syncthreads();
    if ((tx >> 3) == (r & 1)) {
      const int c0 = (tx & 7) * 4;
#pragma unroll
      for (int a = 0; a < 8; a++) {
        const int m = ty * 8 + a;
        float4 val = c2[a][r >> 1];
        tb[m * 32 + ((c0 + 0 + m) & 31)] = val.x;
        tb[m * 32 + ((c0 + 1 + m) & 31)] = val.y;
        tb[m * 32 + ((c0 + 2 + m) & 31)] = val.z;
        tb[m * 32 + ((c0 + 3 + m) & 31)] = val.w;
      }
    }
    __syncthreads();
    const int nl = t >> 3, mq = t & 7;
    float* Trow = T + (size_t)(bB * 1024 + nt0 + (r >> 1) * 64 + (r & 1) * 32 + nl) * 1024 + i0;
#pragma unroll
    for (int l = 0; l < 4; l++) {
      const int mb = (l * 8 + mq) * 4;
      float4 o;
      o.x = tb[(mb + 0) * 32 + ((nl + mb + 0) & 31)];
      o.y = tb[(mb + 1) * 32 + ((nl + mb + 1) & 31)];
      o.z = tb[(mb + 2) * 32 + ((nl + mb + 2) & 31)];
      o.w = tb[(mb + 3) * 32 + ((nl + mb + 3) & 31)];
      *(float4*)(Trow + mb) = o;
    }
  }
}

// ---------------------------------------------------------------------------
// K2a v5: no-LDS stats (fallback path, unchanged from the 956us baseline).
// ---------------------------------------------------------------------------
__global__ __launch_bounds__(256) void attn_stats_v5(
    const float* __restrict__ qT, const float* __restrict__ kT,
    float* __restrict__ Mm, float* __restrict__ Ml)
{
  const int t  = threadIdx.x;
  const int bx = blockIdx.x;
  const int b  = bx >> 8;
  const int it = (bx >> 3) & 31;
  const int js = bx & 7;
  const int wv = t >> 6;
  const int l  = t & 63;
  const int ih = l >> 5;
  const int jg = l & 31;
  const int i0w = __builtin_amdgcn_readfirstlane(it * 32 + wv * 8);
  const int iq = i0w + ih * 4;
  const int jq = js * 128 + jg * 4;

  const float scale = 0.03125f;

  for (int h = 0; h < 16; h++) {
    const size_t base = (size_t)(b * 1024 + h * 64) * 1024;
    float4 acc[4];
#pragma unroll
    for (int ii = 0; ii < 4; ii++) acc[ii] = make_float4(0.f, 0.f, 0.f, 0.f);

#pragma unroll 4
    for (int d = 0; d < 64; d++) {
      const float4 qv = *(const float4*)(qT + base + (size_t)d * 1024 + iq);
      const float4 kv = *(const float4*)(kT + base + (size_t)d * 1024 + jq);
      FMA4(acc[0], qv.x, kv);
      FMA4(acc[1], qv.y, kv);
      FMA4(acc[2], qv.z, kv);
      FMA4(acc[3], qv.w, kv);
    }

#pragma unroll
    for (int ii = 0; ii < 4; ii++) {
      const float s0 = acc[ii].x * scale;
      const float s1 = acc[ii].y * scale;
      const float s2 = acc[ii].z * scale;
      const float s3 = acc[ii].w * scale;
      float mx = fmaxf(fmaxf(s0, s1), fmaxf(s2, s3));
      mx = fmaxf(mx, __shfl_xor(mx, 1));
      mx = fmaxf(mx, __shfl_xor(mx, 2));
      mx = fmaxf(mx, __shfl_xor(mx, 4));
      mx = fmaxf(mx, __shfl_xor(mx, 8));
      mx = fmaxf(mx, __shfl_xor(mx, 16));
      float ss = __expf(s0 - mx) + __expf(s1 - mx) +
                 __expf(s2 - mx) + __expf(s3 - mx);
      ss += __shfl_xor(ss, 1);
      ss += __shfl_xor(ss, 2);
      ss += __shfl_xor(ss, 4);
      ss += __shfl_xor(ss, 8);
      ss += __shfl_xor(ss, 16);
      if (jg == ii) {
        const int idx = (((b * 16 + h) * 1024 + iq + ii) << 3) + js;
        Mm[idx] = mx;
        Ml[idx] = ss;
      }
    }
  }
}

// ---------------------------------------------------------------------------
// K2a v6: identical dot/stats, PLUS stores E = exp(s - m_slice) to Sp
// [b][h][i][j] fp32 (the values it already computes for the row sums).
// Store: float4 per (ii,h); lanes jg 0..31 -> 512B contiguous per row.
// ---------------------------------------------------------------------------
__global__ __launch_bounds__(256) void attn_stats_v6(
    const float* __restrict__ qT, const float* __restrict__ kT,
    float* __restrict__ Mm, float* __restrict__ Ml, float* __restrict__ Sp)
{
  const int t  = threadIdx.x;
  const int bx = blockIdx.x;
  const int b  = bx >> 8;
  const int it = (bx >> 3) & 31;
  const int js = bx & 7;
  const int wv = t >> 6;
  const int l  = t & 63;
  const int ih = l >> 5;
  const int jg = l & 31;
  const int i0w = __builtin_amdgcn_readfirstlane(it * 32 + wv * 8);
  const int iq = i0w + ih * 4;
  const int jq = js * 128 + jg * 4;

  const float scale = 0.03125f;

  for (int h = 0; h < 16; h++) {
    const size_t base = (size_t)(b * 1024 + h * 64) * 1024;
    float4 acc[4];
#pragma unroll
    for (int ii = 0; ii < 4; ii++) acc[ii] = make_float4(0.f, 0.f, 0.f, 0.f);

#pragma unroll 4
    for (int d = 0; d < 64; d++) {
      const float4 qv = *(const float4*)(qT + base + (size_t)d * 1024 + iq);
      const float4 kv = *(const float4*)(kT + base + (size_t)d * 1024 + jq);
      FMA4(acc[0], qv.x, kv);
      FMA4(acc[1], qv.y, kv);
      FMA4(acc[2], qv.z, kv);
      FMA4(acc[3], qv.w, kv);
    }

#pragma unroll
    for (int ii = 0; ii < 4; ii++) {
      const float s0 = acc[ii].x * scale;
      const float s1 = acc[ii].y * scale;
      const float s2 = acc[ii].z * scale;
      const float s3 = acc[ii].w * scale;
      float mx = fmaxf(fmaxf(s0, s1), fmaxf(s2, s3));
      mx = fmaxf(mx, __shfl_xor(mx, 1));
      mx = fmaxf(mx, __shfl_xor(mx, 2));
      mx = fmaxf(mx, __shfl_xor(mx, 4));
      mx = fmaxf(mx, __shfl_xor(mx, 8));
      mx = fmaxf(mx, __shfl_xor(mx, 16));
      const float e0 = __expf(s0 - mx);
      const float e1 = __expf(s1 - mx);
      const float e2 = __expf(s2 - mx);
      const float e3 = __expf(s3 - mx);
      *(float4*)&Sp[((size_t)((b * 16 + h) * 1024) + iq + ii) * 1024 + jq] =
          make_float4(e0, e1, e2, e3);
      float ss = e0 + e1 + e2 + e3;
      ss += __shfl_xor(ss, 1);
      ss += __shfl_xor(ss, 2);
      ss += __shfl_xor(ss, 4);
      ss += __shfl_xor(ss, 8);
      ss += __shfl_xor(ss, 16);
      if (jg == ii) {
        const int idx = (((b * 16 + h) * 1024 + iq + ii) << 3) + js;
        Mm[idx] = mx;
        Ml[idx] = ss;
      }
    }
  }
}

// packed key: monotone(float) << 32 | (1023 - j); atomicMax == (>, tie: min j)
__device__ inline unsigned long long mkkey(float v, int j) {
  unsigned u = __float_as_uint(v);
  u = (u & 0x80000000u) ? ~u : (u | 0x80000000u);
  return ((unsigned long long)u << 32) | (unsigned)(1023 - j);
}

// ---------------------------------------------------------------------------
// K2b v5 (fallback): full dot-recompute select, the 365us baseline kernel.
// ---------------------------------------------------------------------------
__global__ __launch_bounds__(256) void attn_select_v5(
    const float* __restrict__ qT, const float* __restrict__ kT,
    const float* __restrict__ Mm, const float* __restrict__ Ml,
    const float* __restrict__ Wt, const float* __restrict__ ln_g,
    const float* __restrict__ ln_b, unsigned long long* __restrict__ HiKey)
{
  __shared__ __align__(16) float smem[64 * 271 + 512];
  float* ptile = smem;
  float* mred  = smem + 64 * 271;
  float* rred  = mred + 256;

  const int t  = threadIdx.x;
  const int bx = blockIdx.x;
  const int b  = bx >> 10;
  const int it = (bx >> 4) & 63;
  const int js = bx & 15;
  const int i0 = it << 4;
  const int j0 = js << 6;

  const float scale = 0.03125f;

  {
    const int base = (((b * 16 + (t >> 4)) * 1024 + i0 + (t & 15)) << 3);
    const float4 ma = *(const float4*)&Mm[base];
    const float4 mb = *(const float4*)&Mm[base + 4];
    const float4 la = *(const float4*)&Ml[base];
    const float4 lb = *(const float4*)&Ml[base + 4];
    float M = fmaxf(fmaxf(fmaxf(ma.x, ma.y), fmaxf(ma.z, ma.w)),
                    fmaxf(fmaxf(mb.x, mb.y), fmaxf(mb.z, mb.w)));
    float L = la.x * __expf(ma.x - M) + la.y * __expf(ma.y - M) +
              la.z * __expf(ma.z - M) + la.w * __expf(ma.w - M) +
              lb.x * __expf(mb.x - M) + lb.y * __expf(mb.y - M) +
              lb.z * __expf(mb.z - M) + lb.w * __expf(mb.w - M);
    mred[t] = M;
    rred[t] = 1.0f / L;
  }
  __syncthreads();

  const int wv = t >> 6;
  const int l  = t & 63;
  const int jq = l & 15;
  const int ig = l >> 4;
  const int iq = i0 + ig * 4;
  const int jcol = j0 + jq * 4;

#pragma unroll
  for (int hl = 0; hl < 4; hl++) {
    const int h = wv * 4 + hl;
    const size_t base = (size_t)(b * 1024 + h * 64) * 1024;
    float4 acc[4];
#pragma unroll
    for (int ii = 0; ii < 4; ii++) acc[ii] = make_float4(0.f, 0.f, 0.f, 0.f);

#pragma unroll 4
    for (int d = 0; d < 64; d++) {
      const float4 qv = *(const float4*)(qT + base + (size_t)d * 1024 + iq);
      const float4 kv = *(const float4*)(kT + base + (size_t)d * 1024 + jcol);
      FMA4(acc[0], qv.x, kv);
      FMA4(acc[1], qv.y, kv);
      FMA4(acc[2], qv.z, kv);
      FMA4(acc[3], qv.w, kv);
    }

    const int hrot = (h + jq) & 15;
#pragma unroll
    for (int ii = 0; ii < 4; ii++) {
      const int iL = ig * 4 + ii;
      const float m = mred[h * 16 + iL];
      const float r = rred[h * 16 + iL];
      const float a4[4] = {acc[ii].x, acc[ii].y, acc[ii].z, acc[ii].w};
#pragma unroll
      for (int jj = 0; jj < 4; jj++) {
        const int j = jq * 4 + jj;
        const float p = __expf(a4[jj] * scale - m) * r;
        ptile[j * 271 + iL * 17 + hrot] = p;
      }
    }
  }
  __syncthreads();

  const int i2 = t >> 4;
  const int g  = (t >> 2) & 3;
  const int hq = t & 3;

  float wtr[4][16], gr[4], br[4];
#pragma unroll
  for (int a = 0; a < 4; a++) {
#pragma unroll
    for (int h2 = 0; h2 < 16; h2++) wtr[a][h2] = Wt[(hq * 4 + a) * 16 + h2];
    gr[a] = ln_g[hq * 4 + a];
    br[a] = ln_b[hq * 4 + a];
  }
  float bv[4]; int bix[4];
#pragma unroll
  for (int a = 0; a < 4; a++) { bv[a] = -1e30f; bix[a] = 0; }

#pragma unroll
  for (int jj = 0; jj < 16; jj++) {
    const int j = g * 16 + jj;
    const int jr = j >> 2;
    float pv[16];
#pragma unroll
    for (int h2 = 0; h2 < 16; h2++)
      pv[h2] = ptile[j * 271 + i2 * 17 + ((h2 + jr) & 15)];
    float mix[4];
#pragma unroll
    for (int a = 0; a < 4; a++) {
      float s0 = 0.f;
#pragma unroll
      for (int h2 = 0; h2 < 16; h2++) s0 = fmaf(pv[h2], wtr[a][h2], s0);
      mix[a] = s0;
    }
    float s1 = mix[0] + mix[1] + mix[2] + mix[3];
    s1 += __shfl_xor(s1, 1);
    s1 += __shfl_xor(s1, 2);
    const float mu = s1 * 0.0625f;
    float s2 = 0.f;
#pragma unroll
    for (int a = 0; a < 4; a++) { const float dd = mix[a] - mu; s2 = fmaf(dd, dd, s2); }
    s2 += __shfl_xor(s2, 1);
    s2 += __shfl_xor(s2, 2);
    const float rstd = rsqrtf(s2 * 0.0625f + 1e-5f);
    const int jg2 = j0 + j;
#pragma unroll
    for (int a = 0; a < 4; a++) {
      const float nv = (mix[a] - mu) * rstd * gr[a] + br[a];
      if (nv > bv[a]) { bv[a] = nv; bix[a] = jg2; }
    }
  }

#pragma unroll
  for (int a = 0; a < 4; a++) {
    float v = bv[a]; int ix = bix[a];
    {
      const float ov = __shfl_xor(v, 4);
      const int oi = __shfl_xor(ix, 4);
      if (ov > v || (ov == v && oi < ix)) { v = ov; ix = oi; }
    }
    {
      const float ov = __shfl_xor(v, 8);
      const int oi = __shfl_xor(ix, 8);
      if (ov > v || (ov == v && oi < ix)) { v = ov; ix = oi; }
    }
    bv[a] = v; bix[a] = ix;
  }

  if (g == 0) {
#pragma unroll
    for (int a = 0; a < 4; a++) {
      const int cell = (b * 16 + hq * 4 + a) * 1024 + i0 + i2;
      atomicMax(&HiKey[cell], mkkey(bv[a], bix[a]));
    }
  }
}

// ---------------------------------------------------------------------------
// K2b v11: NO dot phase. grid = b(4) x it(64 x 16i) x js(16 x 64j) = 4096,
// 256 thr, tile 16i x 64j x 16h (one 128-j stats slice per block: si=js>>1).
// Prologue: per (h,iL) compute M,L over 8 slices and f = exp(m_si - M)/L.
// E-stream: 8 passes x 32 rows; thread covers (rowid = rr*32 + t>>3,
// jseg = (t&7)*8): 2x float4 loads (256B/row contiguous), p = E*f,
// rotated ptile writes. Mix/LN/argmax: v5 verbatim.
// ---------------------------------------------------------------------------
__global__ __launch_bounds__(256) void attn_select_v11(
    const float* __restrict__ Sp,
    const float* __restrict__ Mm, const float* __restrict__ Ml,
    const float* __restrict__ Wt, const float* __restrict__ ln_g,
    const float* __restrict__ ln_b, unsigned long long* __restrict__ HiKey)
{
  __shared__ __align__(16) float smem[64 * 271 + 256];
  float* ptile = smem;                 // j*271 + i_local*17 + hrot
  float* fred  = smem + 64 * 271;      // [h*16 + i_local] = exp(m_si - M)/L

  const int t  = threadIdx.x;
  const int bx = blockIdx.x;
  const int b  = bx >> 10;
  const int it = (bx >> 4) & 63;
  const int js = bx & 15;
  const int i0 = it << 4;
  const int j0 = js << 6;

  // prologue: merge-8 stats + block-slice factor (t == h*16 + i_local)
  {
    const int base = (((b * 16 + (t >> 4)) * 1024 + i0 + (t & 15)) << 3);
    const float4 ma = *(const float4*)&Mm[base];
    const float4 mb = *(const float4*)&Mm[base + 4];
    const float4 la = *(const float4*)&Ml[base];
    const float4 lb = *(const float4*)&Ml[base + 4];
    float M = fmaxf(fmaxf(fmaxf(ma.x, ma.y), fmaxf(ma.z, ma.w)),
                    fmaxf(fmaxf(mb.x, mb.y), fmaxf(mb.z, mb.w)));
    float L = la.x * __expf(ma.x - M) + la.y * __expf(ma.y - M) +
              la.z * __expf(ma.z - M) + la.w * __expf(ma.w - M) +
              lb.x * __expf(mb.x - M) + lb.y * __expf(mb.y - M) +
              lb.z * __expf(mb.z - M) + lb.w * __expf(mb.w - M);
    const int si = js >> 1;               // block's 128-j slice (uniform)
    const float4 mv = (si & 4) ? mb : ma;
    const int s2 = si & 3;
    const float msl = (s2 == 0) ? mv.x : (s2 == 1) ? mv.y
                    : (s2 == 2) ? mv.z : mv.w;
    fred[t] = __expf(msl - M) / L;
  }
  __syncthreads();

  // E-stream phase: p = E * f -> rotated ptile
#pragma unroll
  for (int rr = 0; rr < 8; rr++) {
    const int rowid = rr * 32 + (t >> 3);   // h*16 + iL
    const int h  = rowid >> 4;
    const int iL = rowid & 15;
    const int jseg = (t & 7) * 8;
    const float f = fred[rowid];
    const float* src = Sp + ((size_t)(b * 16 + h) * 1024 + i0 + iL) * 1024
                          + j0 + jseg;
    const float4 e0 = *(const float4*)src;
    const float4 e1 = *(const float4*)(src + 4);
    const float pv8[8] = {e0.x * f, e0.y * f, e0.z * f, e0.w * f,
                          e1.x * f, e1.y * f, e1.z * f, e1.w * f};
#pragma unroll
    for (int k = 0; k < 8; k++) {
      const int j = jseg + k;
      ptile[j * 271 + iL * 17 + ((h + (j >> 2)) & 15)] = pv8[k];
    }
  }
  __syncthreads();

  // ---- mix phase (v5 verbatim) ----
  const int i2 = t >> 4;
  const int g  = (t >> 2) & 3;
  const int hq = t & 3;

  float wtr[4][16], gr[4], br[4];
#pragma unroll
  for (int a = 0; a < 4; a++) {
#pragma unroll
    for (int h2 = 0; h2 < 16; h2++) wtr[a][h2] = Wt[(hq * 4 + a) * 16 + h2];
    gr[a] = ln_g[hq * 4 + a];
    br[a] = ln_b[hq * 4 + a];
  }
  float bv[4]; int bix[4];
#pragma unroll
  for (int a = 0; a < 4; a++) { bv[a] = -1e30f; bix[a] = 0; }

#pragma unroll
  for (int jj = 0; jj < 16; jj++) {
    const int j = g * 16 + jj;
    const int jr = j >> 2;
    float pv[16];
#pragma unroll
    for (int h2 = 0; h2 < 16; h2++)
      pv[h2] = ptile[j * 271 + i2 * 17 + ((h2 + jr) & 15)];
    float mix[4];
#pragma unroll
    for (int a = 0; a < 4; a++) {
      float s0 = 0.f;
#pragma unroll
      for (int h2 = 0; h2 < 16; h2++) s0 = fmaf(pv[h2], wtr[a][h2], s0);
      mix[a] = s0;
    }
    float s1 = mix[0] + mix[1] + mix[2] + mix[3];
    s1 += __shfl_xor(s1, 1);
    s1 += __shfl_xor(s1, 2);
    const float mu = s1 * 0.0625f;
    float s2 = 0.f;
#pragma unroll
    for (int a = 0; a < 4; a++) { const float dd = mix[a] - mu; s2 = fmaf(dd, dd, s2); }
    s2 += __shfl_xor(s2, 1);
    s2 += __shfl_xor(s2, 2);
    const float rstd = rsqrtf(s2 * 0.0625f + 1e-5f);
    const int jg2 = j0 + j;
#pragma unroll
    for (int a = 0; a < 4; a++) {
      const float nv = (mix[a] - mu) * rstd * gr[a] + br[a];
      if (nv > bv[a]) { bv[a] = nv; bix[a] = jg2; }
    }
  }

  // merge over the 4 g-lanes (ties -> smaller j), then one atomic per (a,i)
#pragma unroll
  for (int a = 0; a < 4; a++) {
    float v = bv[a]; int ix = bix[a];
    {
      const float ov = __shfl_xor(v, 4);
      const int oi = __shfl_xor(ix, 4);
      if (ov > v || (ov == v && oi < ix)) { v = ov; ix = oi; }
    }
    {
      const float ov = __shfl_xor(v, 8);
      const int oi = __shfl_xor(ix, 8);
      if (ov > v || (ov == v && oi < ix)) { v = ov; ix = oi; }
    }
    bv[a] = v; bix[a] = ix;
  }

  if (g == 0) {
#pragma unroll
    for (int a = 0; a < 4; a++) {
      const int cell = (b * 16 + hq * 4 + a) * 1024 + i0 + i2;
      atomicMax(&HiKey[cell], mkkey(bv[a], bix[a]));
    }
  }
}

// ---------------------------------------------------------------------------
// K2c: decode key -> gather V rows (unchanged).
// ---------------------------------------------------------------------------
__global__ __launch_bounds__(256) void gather_v4(
    const unsigned long long* __restrict__ HiKey, const float* __restrict__ V,
    float* __restrict__ out)
{
  const int t  = threadIdx.x;
  const int bx = blockIdx.x;
  const int b  = bx >> 6;
  const int it = bx & 63;
  const int i2 = t >> 4;
  const int h  = t & 15;

  const unsigned long long key = HiKey[(b * 16 + h) * 1024 + it * 16 + i2];
  const int j = 1023 - (int)(unsigned)(key & 0xFFFFFFFFull);

  const float* vs = V + (size_t)(b * 1024 + j) * 1024 + h * 64;
  float* dst = out + (size_t)(b * 1024 + it * 16 + i2) * 1024 + h * 64;
#pragma unroll
  for (int w = 0; w < 16; w++)
    *(float4*)(dst + w * 4) = *(const float4*)(vs + w * 4);
}

extern "C" void kernel_launch(void* const* d_in, const int* in_sizes, int n_in,
                              void* d_out, int out_size, void* d_ws, size_t ws_size,
                              hipStream_t stream) {
  const float* x   = (const float*)d_in[0];
  const float* Wq  = (const float*)d_in[1];
  const float* Wkv = (const float*)d_in[2];
  const float* Wt  = (const float*)d_in[3];
  const float* lng = (const float*)d_in[4];
  const float* lnb = (const float*)d_in[5];
  float* out = (float*)d_out;
  float* ws  = (float*)d_ws;
  float* qT = ws;                                     // 4M f
  float* kT = ws + (size_t)4 * 1024 * 1024;           // 4M f
  float* V  = ws + (size_t)8 * 1024 * 1024;           // 4M f
  float* Mm = ws + (size_t)12 * 1024 * 1024;          // 512K f
  float* Ml = Mm + 524288;                            // 512K f
  unsigned long long* HiKey =
      (unsigned long long*)(ws + (size_t)13 * 1024 * 1024);  // 64K x 8B
  float* Sp = ws + (size_t)14 * 1024 * 1024;          // 64M f (256 MB)

  // B-path needs 78M floats = 312 MB of workspace.
  const size_t NEED = (size_t)78 * 1024 * 1024 * 4;
  const bool big_ws = (ws_size >= NEED);

  hipLaunchKernelGGL(qkv_gemm, dim3(24, 32), dim3(256), 0, stream,
                     x, Wq, Wkv, qT, kT, V);
  hipMemsetAsync(HiKey, 0, (size_t)65536 * 8, stream);
  if (big_ws) {
    hipLaunchKernelGGL(attn_stats_v6, dim3(1024), dim3(256), 0, stream,
                       qT, kT, Mm, Ml, Sp);
    hipLaunchKernelGGL(attn_select_v11, dim3(4096), dim3(256), 0, stream,
                       Sp, Mm, Ml, Wt, lng, lnb, HiKey);
  } else {
    hipLaunchKernelGGL(attn_stats_v5, dim3(1024), dim3(256), 0, stream,
                       qT, kT, Mm, Ml);
    hipLaunchKernelGGL(attn_select_v5, dim3(4096), dim3(256), 0, stream,
                       qT, kT, Mm, Ml, Wt, lng, lnb, HiKey);
  }
  hipLaunchKernelGGL(gather_v4, dim3(256), dim3(256), 0, stream,
                     HiKey, V, out);
}